// Round 11
// baseline (57.436 us; speedup 1.0000x reference)
//
#include <hip/hip_runtime.h>
#include <hip/hip_bf16.h>

// Reference collapses: softmax over singleton axis==1 -> attention weights == 1,
// so ctx[b,h] = sum_l fmap[b,l,h], out[b,t,c] = dot(ctx[b,:], W_gen[c,:]) + b_gen[c]
// broadcast over all t. LSTM / embedding / text are dead code.
//
// R10 post-mortem: R8 counters show K2 ~= 12us/rep, VALUBusy 62% -> K2 is
// VALU-ISSUE-bound. R5's K2 spends 512 DPP instrs vs 256 FMAs (reduce after
// only 8 FMAs of accumulation). R11: c-split waves — each lane accumulates a
// 32-element K-chunk before ONE 4-step DPP reduce (64 DPP instrs, no
// cross-wave combine). K1 = R5 verbatim, fp32 throughout.

constexpr int Hd = 512;   // hidden (K)
constexpr int Cd = 4096;  // classes (N)
constexpr int Bd = 64;    // batch (M)
constexpr int Td = 32;    // timesteps (broadcast)
constexpr int Ld = 256;   // FH*FW
constexpr int CG = 32;    // c per block in K2

// all-DPP 16-lane rotate-add; 0x121:ror1 0x122:ror2 0x124:ror4 0x128:ror8
template<int CTRL>
__device__ __forceinline__ float ror_add(float v) {
    int r = __builtin_amdgcn_update_dpp(0, __float_as_int(v), CTRL, 0xF, 0xF, false);
    return v + __int_as_float(r);
}

// ---------------- K1: ctx[row] = sum of 256 contiguous floats ----------------
// grid 1024 x 256thr; wave = 8 rows, loads all issued up front. (R5 verbatim)
__global__ __launch_bounds__(256) void reduce_rows(const float* __restrict__ in,
                                                   float* __restrict__ ctx) {
    const int lane = threadIdx.x & 63;
    const int gw   = blockIdx.x * 4 + (threadIdx.x >> 6);
    const int row0 = gw * 8;
    const float4* in4 = reinterpret_cast<const float4*>(in);

    float4 v[8];
    #pragma unroll
    for (int r = 0; r < 8; ++r)
        v[r] = in4[(size_t)(row0 + r) * 64 + lane];

    float s[8];
    #pragma unroll
    for (int r = 0; r < 8; ++r) {
        float a = v[r].x + v[r].y + v[r].z + v[r].w;
        a += __shfl_xor(a, 16, 64);
        a += __shfl_xor(a, 32, 64);
        a = ror_add<0x121>(a);
        a = ror_add<0x122>(a);
        a = ror_add<0x124>(a);
        a = ror_add<0x128>(a);
        s[r] = a;
    }
    if (lane < 8) {
        float val = s[0];
        #pragma unroll
        for (int r = 1; r < 8; ++r) val = (lane == r) ? s[r] : val;
        ctx[row0 + lane] = val;
    }
}

// ---------------- K2: out[b][t][c] = ctx[b,:]·W[c,:] + bias, bcast over t -------
// grid (Cd/CG=128, Bd/4=16) = 2048 blocks, 4 waves. Same-cx blocks stride 128
// (== 0 mod 8) -> same XCD -> W slice (64KB) L2-resident across 16 b-replicas.
// Wave w owns c-quads {2w, 2w+1}; lane = (cpart, hp): cpart picks c in the
// quad, hp picks K-chunk [hp*32, hp*32+32). 32 FMAs accumulate per (q,bb)
// before a single 4-step DPP reduce over the 16 hp lanes.
__global__ __launch_bounds__(256) void gemm_bcast(const float* __restrict__ ctx,
                                                  const float* __restrict__ Wgen,
                                                  const float* __restrict__ bgen,
                                                  float* __restrict__ out) {
    __shared__ float4 final4[CG];   // [c_local] -> float4 over 4 b  (512B)
    const int tid   = threadIdx.x;
    const int w     = tid >> 6;
    const int lane  = tid & 63;
    const int cpart = lane >> 4;
    const int hp    = lane & 15;
    const int cblk  = blockIdx.x * CG;
    const int b0    = blockIdx.y * 4;

    const float4* W4 = reinterpret_cast<const float4*>(Wgen);
    const float4* X4 = reinterpret_cast<const float4*>(ctx);

    // W registers: wr[q][i] = W[cblk + (2w+q)*4 + cpart][hp*32 + i*4 .. +3]
    // (per lane 128B contiguous; 16 lanes cover the full 2KB row)
    float4 wr[2][8];
    #pragma unroll
    for (int q = 0; q < 2; ++q) {
        const int c = cblk + (w * 2 + q) * 4 + cpart;
        const float4* p = W4 + (size_t)c * 128 + hp * 8;
        #pragma unroll
        for (int i = 0; i < 8; ++i) wr[q][i] = p[i];
    }

    float acc[2][4];
    #pragma unroll
    for (int bb = 0; bb < 4; ++bb) {
        // stream ctx chunk for this b: xr[i] = ctx[b0+bb][hp*32 + i*4 .. +3]
        float4 xr[8];
        const float4* p = X4 + (size_t)(b0 + bb) * 128 + hp * 8;
        #pragma unroll
        for (int i = 0; i < 8; ++i) xr[i] = p[i];

        #pragma unroll
        for (int q = 0; q < 2; ++q) {
            float a = 0.f;
            #pragma unroll
            for (int i = 0; i < 8; ++i) {
                a += wr[q][i].x * xr[i].x + wr[q][i].y * xr[i].y
                   + wr[q][i].z * xr[i].z + wr[q][i].w * xr[i].w;
            }
            acc[q][bb] = a;
        }
    }

    // one 4-step DPP reduce per (q,bb): 32 ror_adds total per thread
    #pragma unroll
    for (int q = 0; q < 2; ++q) {
        #pragma unroll
        for (int bb = 0; bb < 4; ++bb) {
            float a = acc[q][bb];
            a = ror_add<0x128>(a);
            a = ror_add<0x124>(a);
            a = ror_add<0x122>(a);
            a = ror_add<0x121>(a);      // full K sum in every hp lane
            acc[q][bb] = a;
        }
        if (hp == 0) {
            const int qg = w * 2 + q;
            const float bg = bgen[cblk + qg * 4 + cpart];
            final4[qg * 4 + cpart] = make_float4(acc[q][0] + bg, acc[q][1] + bg,
                                                 acc[q][2] + bg, acc[q][3] + bg);
        }
    }
    __syncthreads();

    // stores: R5's proven pattern — thread (cq,bl,tt) stores float4 at
    // t = tt, tt+8, tt+16, tt+24 (256B-coalesced per wave per instr).
    {
        const int cq = tid & 7;
        const int bl = (tid >> 3) & 3;
        const int tt = tid >> 5;
        const float* ff = reinterpret_cast<const float*>(final4);
        float v[4];
        #pragma unroll
        for (int j = 0; j < 4; ++j) {
            const int cl = cq * 4 + j;
            v[j] = ff[cl * 4 + bl];   // final4[cl] = (b0..b0+3) for c=cblk+cl
        }
        const float4 vv = make_float4(v[0], v[1], v[2], v[3]);
        float* o = out + (size_t)(b0 + bl) * Td * Cd + cblk + cq * 4;
        #pragma unroll
        for (int k = 0; k < 4; ++k) {
            const int t = tt + k * 8;
            *reinterpret_cast<float4*>(o + (size_t)t * Cd) = vv;
        }
    }
}

extern "C" void kernel_launch(void* const* d_in, const int* in_sizes, int n_in,
                              void* d_out, int out_size, void* d_ws, size_t ws_size,
                              hipStream_t stream) {
    const float* fmap = (const float*)d_in[0];   // [64,512,8,32]
    const float* Wgen = (const float*)d_in[9];   // [4096,512]
    const float* bgen = (const float*)d_in[10];  // [4096]
    float* out = (float*)d_out;                  // [64,32,4096]
    float* ctx = (float*)d_ws;                   // [64,512] scratch

    reduce_rows<<<dim3((Bd * Hd) / (4 * 8)), dim3(256), 0, stream>>>(fmap, ctx);
    gemm_bcast<<<dim3(Cd / CG, Bd / 4), dim3(256), 0, stream>>>(ctx, Wgen, bgen, out);
}

// Round 12
// 28.658 us; speedup vs baseline: 2.0042x; 2.0042x over previous
//
#include <hip/hip_runtime.h>
#include <hip/hip_bf16.h>

// Reference collapses: softmax over singleton axis==1 -> attention weights == 1,
// so ctx[b,h] = sum_l fmap[b,l,h], out[b,t,c] = dot(ctx[b,:], W_gen[c,:]) + b_gen[c]
// broadcast over all t. LSTM / embedding / text are dead code.
//
// R11 post-mortem: c-split was right (DPP amortization), but the lane mapping
// put 128B stride between adjacent lanes -> 64 cache lines per W-load instr
// (the R1 scatter mistake again) -> latency collapse (VALU 9.5%, occ 19%).
// R12: same c-split + single-reduce, but R5's coalesced lane mapping:
// lane (cpart,hp) reads W4[c*128 + j*16 + hp], 256B contiguous per 16 lanes.

constexpr int Hd = 512;   // hidden (K)
constexpr int Cd = 4096;  // classes (N)
constexpr int Bd = 64;    // batch (M)
constexpr int Td = 32;    // timesteps (broadcast)
constexpr int Ld = 256;   // FH*FW
constexpr int CG = 32;    // c per block in K2

// all-DPP 16-lane rotate-add; 0x121:ror1 0x122:ror2 0x124:ror4 0x128:ror8
template<int CTRL>
__device__ __forceinline__ float ror_add(float v) {
    int r = __builtin_amdgcn_update_dpp(0, __float_as_int(v), CTRL, 0xF, 0xF, false);
    return v + __int_as_float(r);
}

// ---------------- K1: ctx[row] = sum of 256 contiguous floats ----------------
// grid 1024 x 256thr; wave = 8 rows, loads all issued up front. (R5 verbatim)
__global__ __launch_bounds__(256) void reduce_rows(const float* __restrict__ in,
                                                   float* __restrict__ ctx) {
    const int lane = threadIdx.x & 63;
    const int gw   = blockIdx.x * 4 + (threadIdx.x >> 6);
    const int row0 = gw * 8;
    const float4* in4 = reinterpret_cast<const float4*>(in);

    float4 v[8];
    #pragma unroll
    for (int r = 0; r < 8; ++r)
        v[r] = in4[(size_t)(row0 + r) * 64 + lane];

    float s[8];
    #pragma unroll
    for (int r = 0; r < 8; ++r) {
        float a = v[r].x + v[r].y + v[r].z + v[r].w;
        a += __shfl_xor(a, 16, 64);
        a += __shfl_xor(a, 32, 64);
        a = ror_add<0x121>(a);
        a = ror_add<0x122>(a);
        a = ror_add<0x124>(a);
        a = ror_add<0x128>(a);
        s[r] = a;
    }
    if (lane < 8) {
        float val = s[0];
        #pragma unroll
        for (int r = 1; r < 8; ++r) val = (lane == r) ? s[r] : val;
        ctx[row0 + lane] = val;
    }
}

// ---------------- K2: out[b][t][c] = ctx[b,:]·W[c,:] + bias, bcast over t -------
// grid (Cd/CG=128, Bd/4=16) = 2048 blocks, 4 waves. Same-cx blocks stride 128
// (== 0 mod 8) -> same XCD -> W slice (64KB) L2-resident across 16 b-replicas.
// Wave w owns c-quads {2w, 2w+1}. lane = (cpart, hp); for quad q, lane reads
// W4[c*128 + j*16 + hp] j=0..7 (16 hp lanes = 256B contiguous per instr;
// lane hp covers K elems {j*64 + hp*4..+3}). 32 FMAs accumulate per (q,bb),
// then ONE 4-step DPP reduce over the 16 hp lanes. No cross-wave combine.
__global__ __launch_bounds__(256) void gemm_bcast(const float* __restrict__ ctx,
                                                  const float* __restrict__ Wgen,
                                                  const float* __restrict__ bgen,
                                                  float* __restrict__ out) {
    __shared__ float4 final4[CG];   // [c_local] -> float4 over 4 b  (512B)
    const int tid   = threadIdx.x;
    const int w     = tid >> 6;
    const int lane  = tid & 63;
    const int cpart = lane >> 4;
    const int hp    = lane & 15;
    const int cblk  = blockIdx.x * CG;
    const int b0    = blockIdx.y * 4;

    const float4* W4 = reinterpret_cast<const float4*>(Wgen);
    const float4* X4 = reinterpret_cast<const float4*>(ctx);

    // W registers: wr[q][j] = W4[c*128 + j*16 + hp], coalesced (256B/16 lanes)
    float4 wr[2][8];
    #pragma unroll
    for (int q = 0; q < 2; ++q) {
        const int c = cblk + (w * 2 + q) * 4 + cpart;
        const float4* p = W4 + (size_t)c * 128 + hp;
        #pragma unroll
        for (int j = 0; j < 8; ++j) wr[q][j] = p[j * 16];
    }

    float acc[2][4];
    #pragma unroll
    for (int bb = 0; bb < 4; ++bb) {
        // ctx chunk for this b, same lane mapping: xr[j] = X4[b*128 + j*16 + hp]
        float4 xr[8];
        const float4* p = X4 + (size_t)(b0 + bb) * 128 + hp;
        #pragma unroll
        for (int j = 0; j < 8; ++j) xr[j] = p[j * 16];

        #pragma unroll
        for (int q = 0; q < 2; ++q) {
            float a = 0.f;
            #pragma unroll
            for (int j = 0; j < 8; ++j) {
                a += wr[q][j].x * xr[j].x + wr[q][j].y * xr[j].y
                   + wr[q][j].z * xr[j].z + wr[q][j].w * xr[j].w;
            }
            acc[q][bb] = a;
        }
    }

    // one 4-step DPP reduce per (q,bb): 32 ror_adds total per thread
    #pragma unroll
    for (int q = 0; q < 2; ++q) {
        #pragma unroll
        for (int bb = 0; bb < 4; ++bb) {
            float a = acc[q][bb];
            a = ror_add<0x128>(a);
            a = ror_add<0x124>(a);
            a = ror_add<0x122>(a);
            a = ror_add<0x121>(a);      // full K=512 sum in every hp lane
            acc[q][bb] = a;
        }
        if (hp == 0) {
            const int qg = w * 2 + q;
            const float bg = bgen[cblk + qg * 4 + cpart];
            final4[qg * 4 + cpart] = make_float4(acc[q][0] + bg, acc[q][1] + bg,
                                                 acc[q][2] + bg, acc[q][3] + bg);
        }
    }
    __syncthreads();

    // stores: R5's proven pattern — thread (cq,bl,tt) stores float4 at
    // t = tt, tt+8, tt+16, tt+24 (256B-coalesced per wave per instr).
    {
        const int cq = tid & 7;
        const int bl = (tid >> 3) & 3;
        const int tt = tid >> 5;
        const float* ff = reinterpret_cast<const float*>(final4);
        float v[4];
        #pragma unroll
        for (int j = 0; j < 4; ++j) {
            const int cl = cq * 4 + j;
            v[j] = ff[cl * 4 + bl];   // final4[cl] = (b0..b0+3) for c=cblk+cl
        }
        const float4 vv = make_float4(v[0], v[1], v[2], v[3]);
        float* o = out + (size_t)(b0 + bl) * Td * Cd + cblk + cq * 4;
        #pragma unroll
        for (int k = 0; k < 4; ++k) {
            const int t = tt + k * 8;
            *reinterpret_cast<float4*>(o + (size_t)t * Cd) = vv;
        }
    }
}

extern "C" void kernel_launch(void* const* d_in, const int* in_sizes, int n_in,
                              void* d_out, int out_size, void* d_ws, size_t ws_size,
                              hipStream_t stream) {
    const float* fmap = (const float*)d_in[0];   // [64,512,8,32]
    const float* Wgen = (const float*)d_in[9];   // [4096,512]
    const float* bgen = (const float*)d_in[10];  // [4096]
    float* out = (float*)d_out;                  // [64,32,4096]
    float* ctx = (float*)d_ws;                   // [64,512] scratch

    reduce_rows<<<dim3((Bd * Hd) / (4 * 8)), dim3(256), 0, stream>>>(fmap, ctx);
    gemm_bcast<<<dim3(Cd / CG, Bd / 4), dim3(256), 0, stream>>>(ctx, Wgen, bgen, out);
}